// Round 2
// baseline (1909.486 us; speedup 1.0000x reference)
//
#include <hip/hip_runtime.h>
#include <hip/hip_bf16.h>

#define NF 128
#define RBF 20

__device__ __forceinline__ float sspf(float v) {
    // softplus(v) - log(2), numerically stable
    return fmaxf(v, 0.f) + log1pf(__expf(-fabsf(v))) - 0.69314718055994531f;
}

// ---- generic per-row GEMV: out = [ssp](in @ W [+ b]), dual-branch via blockIdx.y
template<bool BIAS, bool ACT>
__global__ __launch_bounds__(128, 2)
void rowmlp_kernel(const float* __restrict__ in0, const float* __restrict__ in1,
                   const float* __restrict__ W0, const float* __restrict__ W1p,
                   const float* __restrict__ b0, const float* __restrict__ b1,
                   float* __restrict__ o0, float* __restrict__ o1, int N)
{
    const int c = threadIdx.x;                    // output column 0..127
    const float* in = blockIdx.y ? in1 : in0;
    const float* W  = blockIdx.y ? W1p : W0;
    float* out      = blockIdx.y ? o1  : o0;
    float bc = 0.f;
    if (BIAS) bc = (blockIdx.y ? b1 : b0)[c];

    // weight column c in registers (static indexing via full unroll)
    float wreg[NF];
    #pragma unroll
    for (int k = 0; k < NF; ++k) wreg[k] = W[k * NF + c];

    __shared__ float row[NF];

    for (int n = blockIdx.x; n < N; n += gridDim.x) {
        __syncthreads();
        row[c] = in[(size_t)n * NF + c];
        __syncthreads();
        float acc = bc;
        #pragma unroll
        for (int k = 0; k < NF; k += 4) {
            float4 r4 = *reinterpret_cast<const float4*>(&row[k]);
            acc = fmaf(r4.x, wreg[k],     acc);
            acc = fmaf(r4.y, wreg[k + 1], acc);
            acc = fmaf(r4.z, wreg[k + 2], acc);
            acc = fmaf(r4.w, wreg[k + 3], acc);
        }
        if (ACT) acc = sspf(acc);
        out[(size_t)n * NF + c] = acc;   // in-place safe: row staged in LDS first
    }
}

// ---- fused edge kernel: Wij = (ssp(f@Wf1+b1)@Wf2 + b2) * rcut; gather+scatter
__global__ __launch_bounds__(128, 2)
void edge_kernel(const float* __restrict__ f_ij,
                 const float* __restrict__ rcut,
                 const int* __restrict__ idx_i,
                 const int* __restrict__ idx_j,
                 const float* __restrict__ Wf1,
                 const float* __restrict__ bf1,
                 const float* __restrict__ Wf2,
                 const float* __restrict__ bf2,
                 const float* __restrict__ xf,
                 const float* __restrict__ yf,
                 float* __restrict__ conv_x,
                 float* __restrict__ conv_y,
                 int E)
{
    const int c = threadIdx.x;

    float w2reg[NF];
    #pragma unroll
    for (int k = 0; k < NF; ++k) w2reg[k] = Wf2[k * NF + c];
    float w1reg[RBF];
    #pragma unroll
    for (int r = 0; r < RBF; ++r) w1reg[r] = Wf1[r * NF + c];
    const float b1c = bf1[c];
    const float b2c = bf2[c];

    __shared__ float h_lds[NF];

    for (int e = blockIdx.x; e < E; e += gridDim.x) {
        // hidden layer: K = 20, all threads read same addresses (broadcast)
        float hacc = b1c;
        #pragma unroll
        for (int r = 0; r < RBF; ++r) {
            hacc = fmaf(f_ij[(size_t)e * RBF + r], w1reg[r], hacc);
        }
        const float h = sspf(hacc);

        __syncthreads();                 // prev iteration readers done
        h_lds[c] = h;
        __syncthreads();

        float acc = b2c;
        #pragma unroll
        for (int k = 0; k < NF; k += 4) {
            float4 h4 = *reinterpret_cast<const float4*>(&h_lds[k]);
            acc = fmaf(h4.x, w2reg[k],     acc);
            acc = fmaf(h4.y, w2reg[k + 1], acc);
            acc = fmaf(h4.z, w2reg[k + 2], acc);
            acc = fmaf(h4.w, w2reg[k + 3], acc);
        }

        const float w = acc * rcut[e];
        const int i = idx_i[e];
        const int j = idx_j[e];

        const float a = yf[(size_t)j * NF + c];   // message into x-side
        const float b = xf[(size_t)i * NF + c];   // message into y-side
        unsafeAtomicAdd(&conv_x[(size_t)i * NF + c], a * w);
        unsafeAtomicAdd(&conv_y[(size_t)j * NF + c], b * w);
    }
}

extern "C" void kernel_launch(void* const* d_in, const int* in_sizes, int n_in,
                              void* d_out, int out_size, void* d_ws, size_t ws_size,
                              hipStream_t stream)
{
    const float* x    = (const float*)d_in[0];
    const float* y    = (const float*)d_in[1];
    const float* f_ij = (const float*)d_in[2];
    const float* rcut = (const float*)d_in[3];
    const int* idx_i  = (const int*)d_in[4];
    const int* idx_j  = (const int*)d_in[5];
    const float* W_in2f   = (const float*)d_in[6];
    const float* W_in2f_y = (const float*)d_in[7];
    const float* Wf1 = (const float*)d_in[8];
    const float* bf1 = (const float*)d_in[9];
    const float* Wf2 = (const float*)d_in[10];
    const float* bf2 = (const float*)d_in[11];
    const float* Wx1 = (const float*)d_in[12];
    const float* bx1 = (const float*)d_in[13];
    const float* Wx2 = (const float*)d_in[14];
    const float* bx2 = (const float*)d_in[15];
    const float* Wy1 = (const float*)d_in[16];
    const float* by1 = (const float*)d_in[17];
    const float* Wy2 = (const float*)d_in[18];
    const float* by2 = (const float*)d_in[19];

    const int N = in_sizes[0] / NF;
    const int E = in_sizes[4];

    float* out = (float*)d_out;
    // d_out doubles as staging: xf/yf live there until edge_kernel completes,
    // then h_x/h_y overwrite them, then the final layer runs in-place.
    float* xf = out;                       // [N*NF]
    float* yf = out + (size_t)N * NF;      // [N*NF]

    float* conv_x = (float*)d_ws;          // [N*NF] fp32
    float* conv_y = conv_x + (size_t)N * NF;

    hipMemsetAsync(conv_x, 0, (size_t)2 * N * NF * sizeof(float), stream);

    // node projections (bias-free, no activation)
    rowmlp_kernel<false, false><<<dim3(2048, 2), 128, 0, stream>>>(
        x, y, W_in2f, W_in2f_y, nullptr, nullptr, xf, yf, N);

    // fused edge filter + gather + scatter-add
    edge_kernel<<<dim3(8192), 128, 0, stream>>>(f_ij, rcut, idx_i, idx_j,
        Wf1, bf1, Wf2, bf2, xf, yf, conv_x, conv_y, E);

    // output MLP layer 1: h = ssp(conv @ W1 + b1)  -> overwrites xf/yf region
    rowmlp_kernel<true, true><<<dim3(2048, 2), 128, 0, stream>>>(
        conv_x, conv_y, Wx1, Wy1, bx1, by1, xf, yf, N);

    // output MLP layer 2: out = h @ W2 + b2  (in-place per-row)
    rowmlp_kernel<true, false><<<dim3(2048, 2), 128, 0, stream>>>(
        xf, yf, Wx2, Wy2, bx2, by2, xf, yf, N);
}